// Round 20
// baseline (80.670 us; speedup 1.0000x reference)
//
#include <hip/hip_runtime.h>
#include <math.h>

#define BATCH 32
#define NA 8400
#define NMAX 32
#define NC 80
#define TOPK 13
#define THREADS 256
#define NF4ROW (NA / 4)          // 2100 float4 per met row
#define NPT4 9                   // ceil(2100/256)
#define TILE 128                 // anchors per metric block (write pattern proven)
#define NTILES 66                // ceil(8400/128)
#define SSTRIDE 81               // LDS score row stride (odd -> conflict-free gather)

// flat output offsets (elements)
#define OFF_BOX 268800
#define OFF_SCR 1344000
#define OFF_FG  22848000
#define OFF_TGT 23116800
#define SCR_ELEMS (OFF_FG - OFF_SCR)   // 21,504,000 floats
#define SCR_F4    (SCR_ELEMS / 4)      // 5,376,000 float4s
#define ZPB_M     2546                 // ceil(SCR_F4 / 2112 metric blocks)

typedef float f32x4 __attribute__((ext_vector_type(4)));   // NT-store-compatible

__device__ __forceinline__ float ciou_f(float gx1, float gy1, float gx2, float gy2,
                                        float px1, float py1, float px2, float py2) {
    const float eps = 1e-7f;
    float iw = fmaxf(fminf(gx2, px2) - fmaxf(gx1, px1), 0.0f);
    float ih = fmaxf(fminf(gy2, py2) - fmaxf(gy1, py1), 0.0f);
    float inter = iw * ih;
    float w1 = gx2 - gx1, h1 = gy2 - gy1 + eps;
    float w2 = px2 - px1, h2 = py2 - py1 + eps;
    float uni = w1 * h1 + w2 * h2 - inter + eps;
    float iou = inter / uni;
    float cw = fmaxf(gx2, px2) - fminf(gx1, px1);
    float ch = fmaxf(gy2, py2) - fminf(gy1, py1);
    float c2 = cw * cw + ch * ch + eps;
    float dx = px1 + px2 - gx1 - gx2;
    float dy = py1 + py2 - gy1 - gy2;
    float rho2 = (dx * dx + dy * dy) / 4.0f;
    float dd = atanf(w2 / h2) - atanf(w1 / h1);
    float v = (float)(4.0 / (M_PI * M_PI)) * dd * dd;
    float alpha = v / (v - iou + (1.0f + eps));
    return iou - (rho2 / c2 + v * alpha);
}

// grid = (66, BATCH), TILE=128, LB(256,3) — R17-proven config (60.5 µs).
// Cached score loads (L3-resident across replays). Zero-fill stores are now
// PLAIN CACHED (not NT): zeros become dirty L2/L3 lines that flush to HBM
// lazily during later kernels, instead of draining synchronously inside
// metric's execution window. Bit-identical arithmetic.
__global__ __launch_bounds__(THREADS, 3) void metric_kernel(
    const float* __restrict__ pd_scores, const float* __restrict__ pd_bboxes,
    const int* __restrict__ gt_labels, const float* __restrict__ gt_bboxes,
    float* __restrict__ met, unsigned int* __restrict__ mask,
    float* __restrict__ zbase) {
    const int b = blockIdx.y;
    const int abase = blockIdx.x * TILE;
    const int tid = threadIdx.x;
    const int na_tile = min(TILE, NA - abase);
    const float eps = 1e-7f;

    if (tid < na_tile) mask[(size_t)b * NA + abase + tid] = 0u;

    __shared__ float ssc[TILE][SSTRIDE];
    __shared__ float4 spbox[TILE];
    __shared__ float sgx1[NMAX], sgy1[NMAX], sgx2[NMAX], sgy2[NMAX];
    __shared__ float sa1[NMAX], sat1[NMAX];
    __shared__ int   slbl[NMAX];

    if (tid < NMAX) {
        float4 g = ((const float4*)gt_bboxes)[b * NMAX + tid];
        float w1 = g.z - g.x, h1 = g.w - g.y + eps;
        sgx1[tid] = g.x; sgy1[tid] = g.y; sgx2[tid] = g.z; sgy2[tid] = g.w;
        sa1[tid]  = w1 * h1;
        sat1[tid] = atanf(w1 / h1);
        slbl[tid] = gt_labels[b * NMAX + tid];
    } else if (tid >= 128) {
        int al = tid - 128;
        if (al < na_tile)
            spbox[al] = ((const float4*)pd_bboxes)[(size_t)b * NA + abase + al];
    }

    // register-staged score load: plain cached float4 loads (L3-friendly)
    const float4* srec4 = (const float4*)(pd_scores + ((size_t)b * NA + abase) * NC);
    const int nf4 = na_tile * 20;
    float4 r[10];
#pragma unroll
    for (int i = 0; i < 10; i++) {
        int f = tid + i * THREADS;
        if (f < nf4) r[i] = srec4[f];
    }
#pragma unroll
    for (int i = 0; i < 10; i++) {
        int f = tid + i * THREADS;
        if (f < nf4) {
            int a = f / 20, c = f % 20;
            float* d = &ssc[a][c * 4];
            d[0] = r[i].x; d[1] = r[i].y; d[2] = r[i].z; d[3] = r[i].w;
        }
    }
    __syncthreads();

    // overlapped score-plane zero-fill — CACHED stores (lazy HBM drain)
    if (zbase) {
        const int bid = b * NTILES + blockIdx.x;
        const size_t zoff = (size_t)bid * ZPB_M;
        f32x4* zp = (f32x4*)zbase + zoff;
        const f32x4 z = { 0.f, 0.f, 0.f, 0.f };
#pragma unroll
        for (int i = 0; i < 10; i++) {
            int j = tid + i * THREADS;
            if (j < ZPB_M && zoff + j < SCR_F4)
                zp[j] = z;
        }
    }

    const int al = tid & (TILE - 1);
    const int gbase = (tid >> 7) * 16;   // 2 groups x 16 gts
    if (al >= na_tile) return;

    float4 p = spbox[al];
    float w2 = p.z - p.x, h2 = p.w - p.y + eps;
    float a2  = w2 * h2;
    float at2 = atanf(w2 / h2);
    const size_t abs_a = (size_t)abase + al;

#pragma unroll
    for (int k = 0; k < 16; k++) {
        int gi = gbase + k;
        float gx1 = sgx1[gi], gy1 = sgy1[gi], gx2 = sgx2[gi], gy2 = sgy2[gi];
        float iw = fmaxf(fminf(gx2, p.z) - fmaxf(gx1, p.x), 0.0f);
        float ih = fmaxf(fminf(gy2, p.w) - fmaxf(gy1, p.y), 0.0f);
        float inter = iw * ih;
        float uni = sa1[gi] + a2 - inter + eps;
        float iou = inter / uni;
        float cw = fmaxf(gx2, p.z) - fminf(gx1, p.x);
        float ch = fmaxf(gy2, p.w) - fminf(gy1, p.y);
        float c2 = cw * cw + ch * ch + eps;
        float dx = p.x + p.z - gx1 - gx2;
        float dy = p.y + p.w - gy1 - gy2;
        float rho2 = (dx * dx + dy * dy) / 4.0f;
        float dd = at2 - sat1[gi];
        float v = (float)(4.0 / (M_PI * M_PI)) * dd * dd;
        float alpha = v / (v - iou + (1.0f + eps));
        float ov = iou - (rho2 / c2 + v * alpha);
        float sc = ssc[al][slbl[gi]];
        float ov2 = ov * ov;
        met[((size_t)b * NMAX + gi) * NA + abs_a] = sc * (ov2 * ov2 * ov2);
    }
}

// One block per (b, gt) row: pure extraction (R12-proven). float4 row loads;
// per-lane top-2 cache + butterfly + pop/rescan; wave 0 merges.
// Tie-break (value desc, index asc) — matches lax.top_k.
__global__ __launch_bounds__(THREADS) void topk_kernel(
    const float* __restrict__ met, unsigned int* __restrict__ mask) {
    const int tid  = threadIdx.x;
    const int lane = tid & 63;
    const int w    = tid >> 6;
    const int bid  = blockIdx.x;
    const int b  = bid >> 5;
    const int gi = bid & 31;
    const f32x4* mrow4 = (const f32x4*)(met + ((size_t)b * NMAX + gi) * NA);

    f32x4 m4[NPT4];
#pragma unroll
    for (int j = 0; j < NPT4; j++) {
        int f = j * THREADS + tid;
        if (f < NF4ROW) m4[j] = mrow4[f];
    }

    float bv0 = -INFINITY, bv1 = -INFINITY;
    int   ba0 = 0x7FFFFFFF, ba1 = 0x7FFFFFFF;
#pragma unroll
    for (int j = 0; j < NPT4; j++) {
        int f = j * THREADS + tid;
        bool vf = (f < NF4ROW);
#pragma unroll
        for (int c = 0; c < 4; c++) {
            float v = vf ? m4[j][c] : -INFINITY;
            int   a = vf ? 4 * f + c : 0x7FFFFFFF;
            bool beats0 = (v > bv0) || (v == bv0 && a < ba0);
            bool beats1 = (v > bv1) || (v == bv1 && a < ba1);
            if (beats0) { bv1 = bv0; ba1 = ba0; bv0 = v; ba0 = a; }
            else if (beats1) { bv1 = v; ba1 = a; }
        }
    }
    bool valid1 = true;

    float rv = -INFINITY; int ra = 0x7FFFFFFF;
    for (int k = 0; k < TOPK; k++) {
        float v = bv0; int a = ba0;
#pragma unroll
        for (int s = 1; s < 64; s <<= 1) {
            float ov = __shfl_xor(v, s);
            int   oa = __shfl_xor(a, s);
            if (ov > v || (ov == v && oa < a)) { v = ov; a = oa; }
        }
        if (lane == k) { rv = v; ra = a; }
        if (ba0 == a) {
            if (valid1) { bv0 = bv1; ba0 = ba1; valid1 = false; }
            else {
                float nv = -INFINITY; int na_ = 0x7FFFFFFF;
#pragma unroll
                for (int j = 0; j < NPT4; j++) {
                    int f = j * THREADS + tid;
                    bool vf = (f < NF4ROW);
#pragma unroll
                    for (int c = 0; c < 4; c++) {
                        float mv = vf ? m4[j][c] : -INFINITY;
                        int   ma = vf ? 4 * f + c : 0x7FFFFFFF;
                        bool below = (mv < v) || (mv == v && ma > a);
                        bool beats = (mv > nv) || (mv == nv && ma < na_);
                        if (below && beats && vf) { nv = mv; na_ = ma; }
                    }
                }
                bv0 = nv; ba0 = na_;
            }
        }
    }

    __shared__ float lv[4 * TOPK];
    __shared__ int   la[4 * TOPK];
    if (lane < TOPK) { lv[w * TOPK + lane] = rv; la[w * TOPK + lane] = ra; }
    __syncthreads();

    if (w == 0) {
        float v = (lane < 4 * TOPK) ? lv[lane] : -INFINITY;
        int   a = (lane < 4 * TOPK) ? la[lane] : 0x7FFFFFFF;
        for (int k = 0; k < TOPK; k++) {
            float wv = v; int wa = a;
#pragma unroll
            for (int s = 1; s < 64; s <<= 1) {
                float ov = __shfl_xor(wv, s);
                int   oa = __shfl_xor(wa, s);
                if (ov > wv || (ov == wv && oa < wa)) { wv = ov; wa = oa; }
            }
            if (lane == 0) atomicOr(&mask[(size_t)b * NA + wa], 1u << gi);
            if (a == wa) { v = -INFINITY; a = 0x7FFFFFFF; }
        }
    }
}

// Fallback pure streaming zero-fill (used only when ws can't hold met).
__global__ __launch_bounds__(THREADS) void zero_scr_kernel(float* __restrict__ out) {
    f32x4* p = (f32x4*)(out + OFF_SCR);
    const f32x4 z = { 0.f, 0.f, 0.f, 0.f };
    const int stride = gridDim.x * THREADS;
    for (int i = blockIdx.x * THREADS + threadIdx.x; i < SCR_F4; i += stride)
        __builtin_nontemporal_store(z, p + i);
}

// Per-anchor resolve + sparse score scatter into the pre-zeroed plane.
__global__ __launch_bounds__(THREADS) void assign_kernel(
    const float* __restrict__ pd_bboxes, const int* __restrict__ gt_labels,
    const float* __restrict__ gt_bboxes, const unsigned int* __restrict__ mask,
    float* __restrict__ out) {
    const int idx = blockIdx.x * THREADS + threadIdx.x;
    const int b = idx / NA;

    unsigned msk = mask[idx];
    int tgt = msk ? (__ffs(msk) - 1) : 0;   // argmax over gt = first set bit
    float4 gb = ((const float4*)gt_bboxes)[b * NMAX + tgt];
    int lbl = gt_labels[b * NMAX + tgt];
    float4 p = ((const float4*)pd_bboxes)[idx];

    float sum = 0.0f;
    int cnt = 0;
    unsigned mm = msk;
    while (mm) {                             // ascending gt order = JAX sum order
        int i = __ffs(mm) - 1;
        mm &= mm - 1;
        float4 g = ((const float4*)gt_bboxes)[b * NMAX + i];
        sum += ciou_f(g.x, g.y, g.z, g.w, p.x, p.y, p.z, p.w);
        cnt++;
    }
    float po = fminf(fmaxf(sum / ((float)cnt + 1e-9f), 0.0f), 1.0f);

    bool fg = (msk != 0);
    __builtin_nontemporal_store(fg ? (float)lbl : 80.0f, &out[idx]);
    f32x4 gbv = { gb.x, gb.y, gb.z, gb.w };
    __builtin_nontemporal_store(gbv, (f32x4*)(out + OFF_BOX) + idx);
    __builtin_nontemporal_store(fg ? 1.0f : 0.0f, &out[OFF_FG + idx]);
    __builtin_nontemporal_store((float)tgt, &out[OFF_TGT + idx]);
    if (fg) out[OFF_SCR + (size_t)idx * NC + lbl] = po;   // sparse one-hot
}

extern "C" void kernel_launch(void* const* d_in, const int* in_sizes, int n_in,
                              void* d_out, int out_size, void* d_ws, size_t ws_size,
                              hipStream_t stream) {
    const float* pd_scores = (const float*)d_in[0];
    const float* pd_bboxes = (const float*)d_in[1];
    // d_in[2] anc_points: unused by reference
    const int*   gt_labels = (const int*)d_in[3];
    const float* gt_bboxes = (const float*)d_in[4];
    // d_in[5] mask_gt: unused by reference (all ones)

    float* out = (float*)d_out;
    unsigned int* mask = (unsigned int*)d_ws;

    const size_t MASK_BYTES = (size_t)BATCH * NA * 4;
    const size_t MET_BYTES  = (size_t)BATCH * NMAX * NA * 4;
    const size_t met_off = (MASK_BYTES + 255) & ~(size_t)255;
    const bool ws_met = (ws_size >= met_off + MET_BYTES);

    float* met = ws_met ? (float*)((char*)d_ws + met_off) : out + OFF_SCR;

    dim3 g1(NTILES, BATCH);
    if (ws_met) {
        metric_kernel<<<g1, THREADS, 0, stream>>>(pd_scores, pd_bboxes,
                                                  gt_labels, gt_bboxes, met, mask,
                                                  out + OFF_SCR);
        topk_kernel<<<BATCH * NMAX, THREADS, 0, stream>>>(met, mask);
    } else {
        metric_kernel<<<g1, THREADS, 0, stream>>>(pd_scores, pd_bboxes,
                                                  gt_labels, gt_bboxes, met, mask,
                                                  nullptr);
        topk_kernel<<<BATCH * NMAX, THREADS, 0, stream>>>(met, mask);
        zero_scr_kernel<<<2048, THREADS, 0, stream>>>(out);
    }
    assign_kernel<<<BATCH * NA / THREADS, THREADS, 0, stream>>>(
        pd_bboxes, gt_labels, gt_bboxes, mask, out);
}

// Round 21
// 79.267 us; speedup vs baseline: 1.0177x; 1.0177x over previous
//
#include <hip/hip_runtime.h>
#include <math.h>

#define BATCH 32
#define NA 8400
#define NMAX 32
#define NC 80
#define TOPK 13
#define THREADS 256
#define NF4ROW (NA / 4)          // 2100 float4 per met row
#define NPT4 9                   // ceil(2100/256)
#define TILE 128                 // anchors per metric block (write pattern proven)
#define NTILES 66                // ceil(8400/128)
#define SSTRIDE 81               // LDS score row stride (odd -> conflict-free gather)

// flat output offsets (elements)
#define OFF_BOX 268800
#define OFF_SCR 1344000
#define OFF_FG  22848000
#define OFF_TGT 23116800
#define SCR_ELEMS (OFF_FG - OFF_SCR)   // 21,504,000 floats
#define SCR_F4    (SCR_ELEMS / 4)      // 5,376,000 float4s
#define ZPB_M     2546                 // ceil(SCR_F4 / 2112 metric blocks)

typedef float f32x4 __attribute__((ext_vector_type(4)));   // NT-store-compatible

__device__ __forceinline__ float ciou_f(float gx1, float gy1, float gx2, float gy2,
                                        float px1, float py1, float px2, float py2) {
    const float eps = 1e-7f;
    float iw = fmaxf(fminf(gx2, px2) - fmaxf(gx1, px1), 0.0f);
    float ih = fmaxf(fminf(gy2, py2) - fmaxf(gy1, py1), 0.0f);
    float inter = iw * ih;
    float w1 = gx2 - gx1, h1 = gy2 - gy1 + eps;
    float w2 = px2 - px1, h2 = py2 - py1 + eps;
    float uni = w1 * h1 + w2 * h2 - inter + eps;
    float iou = inter / uni;
    float cw = fmaxf(gx2, px2) - fminf(gx1, px1);
    float ch = fmaxf(gy2, py2) - fminf(gy1, py1);
    float c2 = cw * cw + ch * ch + eps;
    float dx = px1 + px2 - gx1 - gx2;
    float dy = py1 + py2 - gy1 - gy2;
    float rho2 = (dx * dx + dy * dy) / 4.0f;
    float dd = atanf(w2 / h2) - atanf(w1 / h1);
    float v = (float)(4.0 / (M_PI * M_PI)) * dd * dd;
    float alpha = v / (v - iou + (1.0f + eps));
    return iou - (rho2 / c2 + v * alpha);
}

// grid = (66, BATCH), TILE=128. Thread = (anchor-quad, 4 gts): computes 4x4
// pairs and stores ONE float4 per gt row (4 dwordx4 stores vs 16 dwords).
// Per-anchor a2/atan precomputed once in LDS (was 2x-8x redundant); spbox/sa2
// hoisted to registers before the loop (kills repeated 8-way-conflict reads).
// Same met/mask/zfill address ranges as R17/R19. Bit-identical arithmetic.
__global__ __launch_bounds__(THREADS, 3) void metric_kernel(
    const float* __restrict__ pd_scores, const float* __restrict__ pd_bboxes,
    const int* __restrict__ gt_labels, const float* __restrict__ gt_bboxes,
    float* __restrict__ met, unsigned int* __restrict__ mask,
    float* __restrict__ zbase) {
    const int b = blockIdx.y;
    const int abase = blockIdx.x * TILE;
    const int tid = threadIdx.x;
    const int na_tile = min(TILE, NA - abase);
    const float eps = 1e-7f;

    if (tid < na_tile) mask[(size_t)b * NA + abase + tid] = 0u;

    __shared__ float ssc[TILE][SSTRIDE];
    __shared__ float4 spbox[TILE];
    __shared__ float sa2_[TILE], sat2_[TILE];   // per-anchor area / atan
    __shared__ float sgx1[NMAX], sgy1[NMAX], sgx2[NMAX], sgy2[NMAX];
    __shared__ float sa1[NMAX], sat1[NMAX];
    __shared__ int   slbl[NMAX];

    if (tid < NMAX) {
        float4 g = ((const float4*)gt_bboxes)[b * NMAX + tid];
        float w1 = g.z - g.x, h1 = g.w - g.y + eps;
        sgx1[tid] = g.x; sgy1[tid] = g.y; sgx2[tid] = g.z; sgy2[tid] = g.w;
        sa1[tid]  = w1 * h1;
        sat1[tid] = atanf(w1 / h1);
        slbl[tid] = gt_labels[b * NMAX + tid];
    } else if (tid >= 128) {
        int al = tid - 128;
        if (al < na_tile)
            spbox[al] = ((const float4*)pd_bboxes)[(size_t)b * NA + abase + al];
    }

    // register-staged score load: plain cached float4 loads (L3-friendly)
    const float4* srec4 = (const float4*)(pd_scores + ((size_t)b * NA + abase) * NC);
    const int nf4 = na_tile * 20;
    float4 r[10];
#pragma unroll
    for (int i = 0; i < 10; i++) {
        int f = tid + i * THREADS;
        if (f < nf4) r[i] = srec4[f];
    }
    __syncthreads();   // spbox + gt data ready

    // per-anchor precompute (once per anchor, was redundant per gt-group)
    if (tid < na_tile) {
        float4 p = spbox[tid];
        float w2 = p.z - p.x, h2 = p.w - p.y + eps;
        sa2_[tid]  = w2 * h2;
        sat2_[tid] = atanf(w2 / h2);
    }

#pragma unroll
    for (int i = 0; i < 10; i++) {
        int f = tid + i * THREADS;
        if (f < nf4) {
            int a = f / 20, c = f % 20;
            float* d = &ssc[a][c * 4];
            d[0] = r[i].x; d[1] = r[i].y; d[2] = r[i].z; d[3] = r[i].w;
        }
    }

    // overlapped score-plane zero-fill (cached; lazy HBM drain)
    if (zbase) {
        const int bid = b * NTILES + blockIdx.x;
        const size_t zoff = (size_t)bid * ZPB_M;
        f32x4* zp = (f32x4*)zbase + zoff;
        const f32x4 z = { 0.f, 0.f, 0.f, 0.f };
#pragma unroll
        for (int i = 0; i < 10; i++) {
            int j = tid + i * THREADS;
            if (j < ZPB_M && zoff + j < SCR_F4)
                zp[j] = z;
        }
    }
    __syncthreads();   // ssc + sa2_/sat2_ committed

    const int q  = tid & 31;          // anchor quad
    const int g0 = (tid >> 5) * 4;    // 8 groups x 4 gts = 32 gts
    const int a0 = q * 4;
    if (a0 >= na_tile) return;        // tail block: 80 % 4 == 0, all-or-nothing

    // hoist the 4 anchors' data to registers (single conflicted read each)
    float4 P[4]; float A2[4], AT2[4];
#pragma unroll
    for (int j = 0; j < 4; j++) {
        P[j]   = spbox[a0 + j];
        A2[j]  = sa2_[a0 + j];
        AT2[j] = sat2_[a0 + j];
    }

#pragma unroll
    for (int g = 0; g < 4; g++) {
        const int gi = g0 + g;
        const float gx1 = sgx1[gi], gy1 = sgy1[gi], gx2 = sgx2[gi], gy2 = sgy2[gi];
        const float ga1 = sa1[gi], gat1 = sat1[gi];
        const int   lbl = slbl[gi];
        float4 mv;
#pragma unroll
        for (int j = 0; j < 4; j++) {
            float4 p = P[j];
            float iw = fmaxf(fminf(gx2, p.z) - fmaxf(gx1, p.x), 0.0f);
            float ih = fmaxf(fminf(gy2, p.w) - fmaxf(gy1, p.y), 0.0f);
            float inter = iw * ih;
            float uni = ga1 + A2[j] - inter + eps;
            float iou = inter / uni;
            float cw = fmaxf(gx2, p.z) - fminf(gx1, p.x);
            float ch = fmaxf(gy2, p.w) - fminf(gy1, p.y);
            float c2 = cw * cw + ch * ch + eps;
            float dx = p.x + p.z - gx1 - gx2;
            float dy = p.y + p.w - gy1 - gy2;
            float rho2 = (dx * dx + dy * dy) / 4.0f;
            float dd = AT2[j] - gat1;
            float v = (float)(4.0 / (M_PI * M_PI)) * dd * dd;
            float alpha = v / (v - iou + (1.0f + eps));
            float ov = iou - (rho2 / c2 + v * alpha);
            float sc = ssc[a0 + j][lbl];
            float ov2 = ov * ov;
            ((float*)&mv)[j] = sc * (ov2 * ov2 * ov2);
        }
        ((float4*)(met + ((size_t)b * NMAX + gi) * NA + abase))[q] = mv;
    }
}

// One block per (b, gt) row: pure extraction (R12-proven). float4 row loads;
// per-lane top-2 cache + butterfly + pop/rescan; wave 0 merges.
// Tie-break (value desc, index asc) — matches lax.top_k.
__global__ __launch_bounds__(THREADS) void topk_kernel(
    const float* __restrict__ met, unsigned int* __restrict__ mask) {
    const int tid  = threadIdx.x;
    const int lane = tid & 63;
    const int w    = tid >> 6;
    const int bid  = blockIdx.x;
    const int b  = bid >> 5;
    const int gi = bid & 31;
    const f32x4* mrow4 = (const f32x4*)(met + ((size_t)b * NMAX + gi) * NA);

    f32x4 m4[NPT4];
#pragma unroll
    for (int j = 0; j < NPT4; j++) {
        int f = j * THREADS + tid;
        if (f < NF4ROW) m4[j] = mrow4[f];
    }

    float bv0 = -INFINITY, bv1 = -INFINITY;
    int   ba0 = 0x7FFFFFFF, ba1 = 0x7FFFFFFF;
#pragma unroll
    for (int j = 0; j < NPT4; j++) {
        int f = j * THREADS + tid;
        bool vf = (f < NF4ROW);
#pragma unroll
        for (int c = 0; c < 4; c++) {
            float v = vf ? m4[j][c] : -INFINITY;
            int   a = vf ? 4 * f + c : 0x7FFFFFFF;
            bool beats0 = (v > bv0) || (v == bv0 && a < ba0);
            bool beats1 = (v > bv1) || (v == bv1 && a < ba1);
            if (beats0) { bv1 = bv0; ba1 = ba0; bv0 = v; ba0 = a; }
            else if (beats1) { bv1 = v; ba1 = a; }
        }
    }
    bool valid1 = true;

    float rv = -INFINITY; int ra = 0x7FFFFFFF;
    for (int k = 0; k < TOPK; k++) {
        float v = bv0; int a = ba0;
#pragma unroll
        for (int s = 1; s < 64; s <<= 1) {
            float ov = __shfl_xor(v, s);
            int   oa = __shfl_xor(a, s);
            if (ov > v || (ov == v && oa < a)) { v = ov; a = oa; }
        }
        if (lane == k) { rv = v; ra = a; }
        if (ba0 == a) {
            if (valid1) { bv0 = bv1; ba0 = ba1; valid1 = false; }
            else {
                float nv = -INFINITY; int na_ = 0x7FFFFFFF;
#pragma unroll
                for (int j = 0; j < NPT4; j++) {
                    int f = j * THREADS + tid;
                    bool vf = (f < NF4ROW);
#pragma unroll
                    for (int c = 0; c < 4; c++) {
                        float mv = vf ? m4[j][c] : -INFINITY;
                        int   ma = vf ? 4 * f + c : 0x7FFFFFFF;
                        bool below = (mv < v) || (mv == v && ma > a);
                        bool beats = (mv > nv) || (mv == nv && ma < na_);
                        if (below && beats && vf) { nv = mv; na_ = ma; }
                    }
                }
                bv0 = nv; ba0 = na_;
            }
        }
    }

    __shared__ float lv[4 * TOPK];
    __shared__ int   la[4 * TOPK];
    if (lane < TOPK) { lv[w * TOPK + lane] = rv; la[w * TOPK + lane] = ra; }
    __syncthreads();

    if (w == 0) {
        float v = (lane < 4 * TOPK) ? lv[lane] : -INFINITY;
        int   a = (lane < 4 * TOPK) ? la[lane] : 0x7FFFFFFF;
        for (int k = 0; k < TOPK; k++) {
            float wv = v; int wa = a;
#pragma unroll
            for (int s = 1; s < 64; s <<= 1) {
                float ov = __shfl_xor(wv, s);
                int   oa = __shfl_xor(wa, s);
                if (ov > wv || (ov == wv && oa < wa)) { wv = ov; wa = oa; }
            }
            if (lane == 0) atomicOr(&mask[(size_t)b * NA + wa], 1u << gi);
            if (a == wa) { v = -INFINITY; a = 0x7FFFFFFF; }
        }
    }
}

// Fallback pure streaming zero-fill (used only when ws can't hold met).
__global__ __launch_bounds__(THREADS) void zero_scr_kernel(float* __restrict__ out) {
    f32x4* p = (f32x4*)(out + OFF_SCR);
    const f32x4 z = { 0.f, 0.f, 0.f, 0.f };
    const int stride = gridDim.x * THREADS;
    for (int i = blockIdx.x * THREADS + threadIdx.x; i < SCR_F4; i += stride)
        __builtin_nontemporal_store(z, p + i);
}

// Per-anchor resolve + sparse score scatter into the pre-zeroed plane.
__global__ __launch_bounds__(THREADS) void assign_kernel(
    const float* __restrict__ pd_bboxes, const int* __restrict__ gt_labels,
    const float* __restrict__ gt_bboxes, const unsigned int* __restrict__ mask,
    float* __restrict__ out) {
    const int idx = blockIdx.x * THREADS + threadIdx.x;
    const int b = idx / NA;

    unsigned msk = mask[idx];
    int tgt = msk ? (__ffs(msk) - 1) : 0;   // argmax over gt = first set bit
    float4 gb = ((const float4*)gt_bboxes)[b * NMAX + tgt];
    int lbl = gt_labels[b * NMAX + tgt];
    float4 p = ((const float4*)pd_bboxes)[idx];

    float sum = 0.0f;
    int cnt = 0;
    unsigned mm = msk;
    while (mm) {                             // ascending gt order = JAX sum order
        int i = __ffs(mm) - 1;
        mm &= mm - 1;
        float4 g = ((const float4*)gt_bboxes)[b * NMAX + i];
        sum += ciou_f(g.x, g.y, g.z, g.w, p.x, p.y, p.z, p.w);
        cnt++;
    }
    float po = fminf(fmaxf(sum / ((float)cnt + 1e-9f), 0.0f), 1.0f);

    bool fg = (msk != 0);
    __builtin_nontemporal_store(fg ? (float)lbl : 80.0f, &out[idx]);
    f32x4 gbv = { gb.x, gb.y, gb.z, gb.w };
    __builtin_nontemporal_store(gbv, (f32x4*)(out + OFF_BOX) + idx);
    __builtin_nontemporal_store(fg ? 1.0f : 0.0f, &out[OFF_FG + idx]);
    __builtin_nontemporal_store((float)tgt, &out[OFF_TGT + idx]);
    if (fg) out[OFF_SCR + (size_t)idx * NC + lbl] = po;   // sparse one-hot
}

extern "C" void kernel_launch(void* const* d_in, const int* in_sizes, int n_in,
                              void* d_out, int out_size, void* d_ws, size_t ws_size,
                              hipStream_t stream) {
    const float* pd_scores = (const float*)d_in[0];
    const float* pd_bboxes = (const float*)d_in[1];
    // d_in[2] anc_points: unused by reference
    const int*   gt_labels = (const int*)d_in[3];
    const float* gt_bboxes = (const float*)d_in[4];
    // d_in[5] mask_gt: unused by reference (all ones)

    float* out = (float*)d_out;
    unsigned int* mask = (unsigned int*)d_ws;

    const size_t MASK_BYTES = (size_t)BATCH * NA * 4;
    const size_t MET_BYTES  = (size_t)BATCH * NMAX * NA * 4;
    const size_t met_off = (MASK_BYTES + 255) & ~(size_t)255;
    const bool ws_met = (ws_size >= met_off + MET_BYTES);

    float* met = ws_met ? (float*)((char*)d_ws + met_off) : out + OFF_SCR;

    dim3 g1(NTILES, BATCH);
    if (ws_met) {
        metric_kernel<<<g1, THREADS, 0, stream>>>(pd_scores, pd_bboxes,
                                                  gt_labels, gt_bboxes, met, mask,
                                                  out + OFF_SCR);
        topk_kernel<<<BATCH * NMAX, THREADS, 0, stream>>>(met, mask);
    } else {
        metric_kernel<<<g1, THREADS, 0, stream>>>(pd_scores, pd_bboxes,
                                                  gt_labels, gt_bboxes, met, mask,
                                                  nullptr);
        topk_kernel<<<BATCH * NMAX, THREADS, 0, stream>>>(met, mask);
        zero_scr_kernel<<<2048, THREADS, 0, stream>>>(out);
    }
    assign_kernel<<<BATCH * NA / THREADS, THREADS, 0, stream>>>(
        pd_bboxes, gt_labels, gt_bboxes, mask, out);
}

// Round 22
// 78.779 us; speedup vs baseline: 1.0240x; 1.0062x over previous
//
#include <hip/hip_runtime.h>
#include <math.h>

#define BATCH 32
#define NA 8400
#define NMAX 32
#define NC 80
#define TOPK 13
#define THREADS 256
#define TILE 128                 // anchors per metric block
#define NTILES 66                // ceil(8400/128); last tile has 80 valid anchors
#define LASTV 80                 // valid anchors in tile 65
#define ROWF4 (NTILES * 32)      // 2112 float4 per padded met row
#define NPT4 9                   // ceil(2112/256)
#define SSTRIDE 81               // LDS score row stride (odd -> conflict-free gather)

// flat output offsets (elements)
#define OFF_BOX 268800
#define OFF_SCR 1344000
#define OFF_FG  22848000
#define OFF_TGT 23116800
#define SCR_ELEMS (OFF_FG - OFF_SCR)   // 21,504,000 floats
#define SCR_F4    (SCR_ELEMS / 4)      // 5,376,000 float4s
#define ZPB_M     2546                 // ceil(SCR_F4 / 2112 metric blocks)

typedef float f32x4 __attribute__((ext_vector_type(4)));   // NT-store-compatible

__device__ __forceinline__ float ciou_f(float gx1, float gy1, float gx2, float gy2,
                                        float px1, float py1, float px2, float py2) {
    const float eps = 1e-7f;
    float iw = fmaxf(fminf(gx2, px2) - fmaxf(gx1, px1), 0.0f);
    float ih = fmaxf(fminf(gy2, py2) - fmaxf(gy1, py1), 0.0f);
    float inter = iw * ih;
    float w1 = gx2 - gx1, h1 = gy2 - gy1 + eps;
    float w2 = px2 - px1, h2 = py2 - py1 + eps;
    float uni = w1 * h1 + w2 * h2 - inter + eps;
    float iou = inter / uni;
    float cw = fmaxf(gx2, px2) - fminf(gx1, px1);
    float ch = fmaxf(gy2, py2) - fminf(gy1, py1);
    float c2 = cw * cw + ch * ch + eps;
    float dx = px1 + px2 - gx1 - gx2;
    float dy = py1 + py2 - gy1 - gy2;
    float rho2 = (dx * dx + dy * dy) / 4.0f;
    float dd = atanf(w2 / h2) - atanf(w1 / h1);
    float v = (float)(4.0 / (M_PI * M_PI)) * dd * dd;
    float alpha = v / (v - iou + (1.0f + eps));
    return iou - (rho2 / c2 + v * alpha);
}

// grid = (66, BATCH), TILE=128, thread = (anchor-quad, 4 gts) — R20 compute
// structure. NEW: met layout [b][tile][gt][128] so this block's 32 gt-rows
// land in ONE contiguous 16 KB stream (was 32 x 512 B at 33.6 KB stride —
// DRAM page-locality hypothesis). Tail tile (65) leaves its 48-anchor pad
// unwritten; topk masks it. Bit-identical arithmetic.
__global__ __launch_bounds__(THREADS, 3) void metric_kernel(
    const float* __restrict__ pd_scores, const float* __restrict__ pd_bboxes,
    const int* __restrict__ gt_labels, const float* __restrict__ gt_bboxes,
    float* __restrict__ met, unsigned int* __restrict__ mask,
    float* __restrict__ zbase) {
    const int b = blockIdx.y;
    const int abase = blockIdx.x * TILE;
    const int tid = threadIdx.x;
    const int na_tile = min(TILE, NA - abase);
    const float eps = 1e-7f;

    if (tid < na_tile) mask[(size_t)b * NA + abase + tid] = 0u;

    __shared__ float ssc[TILE][SSTRIDE];
    __shared__ float4 spbox[TILE];
    __shared__ float sa2_[TILE], sat2_[TILE];   // per-anchor area / atan
    __shared__ float sgx1[NMAX], sgy1[NMAX], sgx2[NMAX], sgy2[NMAX];
    __shared__ float sa1[NMAX], sat1[NMAX];
    __shared__ int   slbl[NMAX];

    if (tid < NMAX) {
        float4 g = ((const float4*)gt_bboxes)[b * NMAX + tid];
        float w1 = g.z - g.x, h1 = g.w - g.y + eps;
        sgx1[tid] = g.x; sgy1[tid] = g.y; sgx2[tid] = g.z; sgy2[tid] = g.w;
        sa1[tid]  = w1 * h1;
        sat1[tid] = atanf(w1 / h1);
        slbl[tid] = gt_labels[b * NMAX + tid];
    } else if (tid >= 128) {
        int al = tid - 128;
        if (al < na_tile)
            spbox[al] = ((const float4*)pd_bboxes)[(size_t)b * NA + abase + al];
    }

    // register-staged score load: plain cached float4 loads (L3-friendly)
    const float4* srec4 = (const float4*)(pd_scores + ((size_t)b * NA + abase) * NC);
    const int nf4 = na_tile * 20;
    float4 r[10];
#pragma unroll
    for (int i = 0; i < 10; i++) {
        int f = tid + i * THREADS;
        if (f < nf4) r[i] = srec4[f];
    }
    __syncthreads();   // spbox + gt data ready

    if (tid < na_tile) {
        float4 p = spbox[tid];
        float w2 = p.z - p.x, h2 = p.w - p.y + eps;
        sa2_[tid]  = w2 * h2;
        sat2_[tid] = atanf(w2 / h2);
    }

#pragma unroll
    for (int i = 0; i < 10; i++) {
        int f = tid + i * THREADS;
        if (f < nf4) {
            int a = f / 20, c = f % 20;
            float* d = &ssc[a][c * 4];
            d[0] = r[i].x; d[1] = r[i].y; d[2] = r[i].z; d[3] = r[i].w;
        }
    }

    // overlapped score-plane zero-fill (cached; lazy HBM drain)
    if (zbase) {
        const int bid = b * NTILES + blockIdx.x;
        const size_t zoff = (size_t)bid * ZPB_M;
        f32x4* zp = (f32x4*)zbase + zoff;
        const f32x4 z = { 0.f, 0.f, 0.f, 0.f };
#pragma unroll
        for (int i = 0; i < 10; i++) {
            int j = tid + i * THREADS;
            if (j < ZPB_M && zoff + j < SCR_F4)
                zp[j] = z;
        }
    }
    __syncthreads();   // ssc + sa2_/sat2_ committed

    const int q  = tid & 31;          // anchor quad
    const int g0 = (tid >> 5) * 4;    // 8 groups x 4 gts = 32 gts
    const int a0 = q * 4;
    if (a0 >= na_tile) return;        // tail tile: 80 % 4 == 0, all-or-nothing

    float4 P[4]; float A2[4], AT2[4];
#pragma unroll
    for (int j = 0; j < 4; j++) {
        P[j]   = spbox[a0 + j];
        A2[j]  = sa2_[a0 + j];
        AT2[j] = sat2_[a0 + j];
    }

    // contiguous per-block met base: [b][tile][gt][128]
    float* mblk = met + (((size_t)b * NTILES + blockIdx.x) * NMAX) * TILE;

#pragma unroll
    for (int g = 0; g < 4; g++) {
        const int gi = g0 + g;
        const float gx1 = sgx1[gi], gy1 = sgy1[gi], gx2 = sgx2[gi], gy2 = sgy2[gi];
        const float ga1 = sa1[gi], gat1 = sat1[gi];
        const int   lbl = slbl[gi];
        float4 mv;
#pragma unroll
        for (int j = 0; j < 4; j++) {
            float4 p = P[j];
            float iw = fmaxf(fminf(gx2, p.z) - fmaxf(gx1, p.x), 0.0f);
            float ih = fmaxf(fminf(gy2, p.w) - fmaxf(gy1, p.y), 0.0f);
            float inter = iw * ih;
            float uni = ga1 + A2[j] - inter + eps;
            float iou = inter / uni;
            float cw = fmaxf(gx2, p.z) - fminf(gx1, p.x);
            float ch = fmaxf(gy2, p.w) - fminf(gy1, p.y);
            float c2 = cw * cw + ch * ch + eps;
            float dx = p.x + p.z - gx1 - gx2;
            float dy = p.y + p.w - gy1 - gy2;
            float rho2 = (dx * dx + dy * dy) / 4.0f;
            float dd = AT2[j] - gat1;
            float v = (float)(4.0 / (M_PI * M_PI)) * dd * dd;
            float alpha = v / (v - iou + (1.0f + eps));
            float ov = iou - (rho2 / c2 + v * alpha);
            float sc = ssc[a0 + j][lbl];
            float ov2 = ov * ov;
            ((float*)&mv)[j] = sc * (ov2 * ov2 * ov2);
        }
        ((float4*)(mblk + gi * TILE))[q] = mv;
    }
}

// One block per (b, gt) row over the TILED met layout: float4 f maps to
// tile t = f>>5, within-tile float4 (f&31); anchor of element (f,c) is
// t*128 + 4*(f&31)+c; pad (t==65, al>=80) masked to (-INF, INT_MAX).
// Per-lane top-2 cache + butterfly + pop/rescan; wave 0 merges.
// Tie-break (value desc, index asc) — matches lax.top_k.
__global__ __launch_bounds__(THREADS) void topk_kernel(
    const float* __restrict__ met, unsigned int* __restrict__ mask) {
    const int tid  = threadIdx.x;
    const int lane = tid & 63;
    const int w    = tid >> 6;
    const int bid  = blockIdx.x;
    const int b  = bid >> 5;
    const int gi = bid & 31;
    const f32x4* mb4 = (const f32x4*)met + (size_t)b * NTILES * NMAX * 32;

    f32x4 m4[NPT4];
#pragma unroll
    for (int j = 0; j < NPT4; j++) {
        int f = j * THREADS + tid;
        if (f < ROWF4)
            m4[j] = mb4[(((f >> 5) * NMAX) + gi) * 32 + (f & 31)];
    }

    float bv0 = -INFINITY, bv1 = -INFINITY;
    int   ba0 = 0x7FFFFFFF, ba1 = 0x7FFFFFFF;
#pragma unroll
    for (int j = 0; j < NPT4; j++) {
        int f = j * THREADS + tid;
        bool inrow = (f < ROWF4);
        int t = f >> 5;
#pragma unroll
        for (int c = 0; c < 4; c++) {
            int al = 4 * (f & 31) + c;
            bool vf = inrow && (t < NTILES - 1 || al < LASTV);
            float v = vf ? m4[j][c] : -INFINITY;
            int   a = vf ? t * TILE + al : 0x7FFFFFFF;
            bool beats0 = (v > bv0) || (v == bv0 && a < ba0);
            bool beats1 = (v > bv1) || (v == bv1 && a < ba1);
            if (beats0) { bv1 = bv0; ba1 = ba0; bv0 = v; ba0 = a; }
            else if (beats1) { bv1 = v; ba1 = a; }
        }
    }
    bool valid1 = true;

    float rv = -INFINITY; int ra = 0x7FFFFFFF;
    for (int k = 0; k < TOPK; k++) {
        float v = bv0; int a = ba0;
#pragma unroll
        for (int s = 1; s < 64; s <<= 1) {
            float ov = __shfl_xor(v, s);
            int   oa = __shfl_xor(a, s);
            if (ov > v || (ov == v && oa < a)) { v = ov; a = oa; }
        }
        if (lane == k) { rv = v; ra = a; }
        if (ba0 == a) {
            if (valid1) { bv0 = bv1; ba0 = ba1; valid1 = false; }
            else {
                float nv = -INFINITY; int na_ = 0x7FFFFFFF;
#pragma unroll
                for (int j = 0; j < NPT4; j++) {
                    int f = j * THREADS + tid;
                    bool inrow = (f < ROWF4);
                    int t = f >> 5;
#pragma unroll
                    for (int c = 0; c < 4; c++) {
                        int al = 4 * (f & 31) + c;
                        bool vf = inrow && (t < NTILES - 1 || al < LASTV);
                        float mv = vf ? m4[j][c] : -INFINITY;
                        int   ma = vf ? t * TILE + al : 0x7FFFFFFF;
                        bool below = (mv < v) || (mv == v && ma > a);
                        bool beats = (mv > nv) || (mv == nv && ma < na_);
                        if (below && beats && vf) { nv = mv; na_ = ma; }
                    }
                }
                bv0 = nv; ba0 = na_;
            }
        }
    }

    __shared__ float lv[4 * TOPK];
    __shared__ int   la[4 * TOPK];
    if (lane < TOPK) { lv[w * TOPK + lane] = rv; la[w * TOPK + lane] = ra; }
    __syncthreads();

    if (w == 0) {
        float v = (lane < 4 * TOPK) ? lv[lane] : -INFINITY;
        int   a = (lane < 4 * TOPK) ? la[lane] : 0x7FFFFFFF;
        for (int k = 0; k < TOPK; k++) {
            float wv = v; int wa = a;
#pragma unroll
            for (int s = 1; s < 64; s <<= 1) {
                float ov = __shfl_xor(wv, s);
                int   oa = __shfl_xor(wa, s);
                if (ov > wv || (ov == wv && oa < wa)) { wv = ov; wa = oa; }
            }
            if (lane == 0) atomicOr(&mask[(size_t)b * NA + wa], 1u << gi);
            if (a == wa) { v = -INFINITY; a = 0x7FFFFFFF; }
        }
    }
}

// Fallback pure streaming zero-fill (used only when ws can't hold met).
__global__ __launch_bounds__(THREADS) void zero_scr_kernel(float* __restrict__ out) {
    f32x4* p = (f32x4*)(out + OFF_SCR);
    const f32x4 z = { 0.f, 0.f, 0.f, 0.f };
    const int stride = gridDim.x * THREADS;
    for (int i = blockIdx.x * THREADS + threadIdx.x; i < SCR_F4; i += stride)
        __builtin_nontemporal_store(z, p + i);
}

// Per-anchor resolve + sparse score scatter into the pre-zeroed plane.
__global__ __launch_bounds__(THREADS) void assign_kernel(
    const float* __restrict__ pd_bboxes, const int* __restrict__ gt_labels,
    const float* __restrict__ gt_bboxes, const unsigned int* __restrict__ mask,
    float* __restrict__ out) {
    const int idx = blockIdx.x * THREADS + threadIdx.x;
    const int b = idx / NA;

    unsigned msk = mask[idx];
    int tgt = msk ? (__ffs(msk) - 1) : 0;   // argmax over gt = first set bit
    float4 gb = ((const float4*)gt_bboxes)[b * NMAX + tgt];
    int lbl = gt_labels[b * NMAX + tgt];
    float4 p = ((const float4*)pd_bboxes)[idx];

    float sum = 0.0f;
    int cnt = 0;
    unsigned mm = msk;
    while (mm) {                             // ascending gt order = JAX sum order
        int i = __ffs(mm) - 1;
        mm &= mm - 1;
        float4 g = ((const float4*)gt_bboxes)[b * NMAX + i];
        sum += ciou_f(g.x, g.y, g.z, g.w, p.x, p.y, p.z, p.w);
        cnt++;
    }
    float po = fminf(fmaxf(sum / ((float)cnt + 1e-9f), 0.0f), 1.0f);

    bool fg = (msk != 0);
    __builtin_nontemporal_store(fg ? (float)lbl : 80.0f, &out[idx]);
    f32x4 gbv = { gb.x, gb.y, gb.z, gb.w };
    __builtin_nontemporal_store(gbv, (f32x4*)(out + OFF_BOX) + idx);
    __builtin_nontemporal_store(fg ? 1.0f : 0.0f, &out[OFF_FG + idx]);
    __builtin_nontemporal_store((float)tgt, &out[OFF_TGT + idx]);
    if (fg) out[OFF_SCR + (size_t)idx * NC + lbl] = po;   // sparse one-hot
}

extern "C" void kernel_launch(void* const* d_in, const int* in_sizes, int n_in,
                              void* d_out, int out_size, void* d_ws, size_t ws_size,
                              hipStream_t stream) {
    const float* pd_scores = (const float*)d_in[0];
    const float* pd_bboxes = (const float*)d_in[1];
    // d_in[2] anc_points: unused by reference
    const int*   gt_labels = (const int*)d_in[3];
    const float* gt_bboxes = (const float*)d_in[4];
    // d_in[5] mask_gt: unused by reference (all ones)

    float* out = (float*)d_out;
    unsigned int* mask = (unsigned int*)d_ws;

    const size_t MASK_BYTES = (size_t)BATCH * NA * 4;
    const size_t MET_BYTES  = (size_t)BATCH * NTILES * NMAX * TILE * 4;  // padded
    const size_t met_off = (MASK_BYTES + 255) & ~(size_t)255;
    const bool ws_met = (ws_size >= met_off + MET_BYTES);

    float* met = ws_met ? (float*)((char*)d_ws + met_off) : out + OFF_SCR;

    dim3 g1(NTILES, BATCH);
    if (ws_met) {
        metric_kernel<<<g1, THREADS, 0, stream>>>(pd_scores, pd_bboxes,
                                                  gt_labels, gt_bboxes, met, mask,
                                                  out + OFF_SCR);
        topk_kernel<<<BATCH * NMAX, THREADS, 0, stream>>>(met, mask);
    } else {
        metric_kernel<<<g1, THREADS, 0, stream>>>(pd_scores, pd_bboxes,
                                                  gt_labels, gt_bboxes, met, mask,
                                                  nullptr);
        topk_kernel<<<BATCH * NMAX, THREADS, 0, stream>>>(met, mask);
        zero_scr_kernel<<<2048, THREADS, 0, stream>>>(out);
    }
    assign_kernel<<<BATCH * NA / THREADS, THREADS, 0, stream>>>(
        pd_bboxes, gt_labels, gt_bboxes, mask, out);
}